// Round 1
// baseline (795.590 us; speedup 1.0000x reference)
//
#include <hip/hip_runtime.h>

#define NBINS 15

// One wave (64 lanes) per row. Row = 100 contiguous floats (400 B, 16B-aligned),
// read coalesced in 2 passes. Reduce sum / sumsq / max+argmax / p[label] via
// wave shuffles; lane 0 bins the row into per-block LDS accumulators; one set
// of global atomics per block at the end.
__global__ __launch_bounds__(256) void ece_rows(const float* __restrict__ probs,
                                                const int* __restrict__ labels,
                                                int N, int C,
                                                double* __restrict__ g_bri,
                                                float* __restrict__ g_cnt,
                                                float* __restrict__ g_conf,
                                                float* __restrict__ g_acc) {
    __shared__ float s_cnt[NBINS], s_conf[NBINS], s_acc[NBINS];
    __shared__ float s_bri;
    const int tid = threadIdx.x;
    if (tid < NBINS) { s_cnt[tid] = 0.f; s_conf[tid] = 0.f; s_acc[tid] = 0.f; }
    if (tid == 0) s_bri = 0.f;
    __syncthreads();

    const int lane   = tid & 63;
    const int wave   = (int)((blockIdx.x * blockDim.x + tid) >> 6);
    const int nwaves = (int)((gridDim.x * blockDim.x) >> 6);
    float wbri = 0.f;  // per-wave brier partial (lives in lane 0's register)

    for (int r = wave; r < N; r += nwaves) {
        const float* row = probs + (size_t)r * (size_t)C;
        const int label = labels[r];

        float lmax = -1.f;          // probs in [0,1): anything beats -1
        int   lidx = 0x7fffffff;    // tie-break: smaller index wins
        float lsum = 0.f, lsq = 0.f, lpl = 0.f;
        for (int c = lane; c < C; c += 64) {
            float v = row[c];
            lsum += v;
            lsq   = fmaf(v, v, lsq);
            if (v > lmax) { lmax = v; lidx = c; }
            if (c == label) lpl = v;
        }
        // full-wave (64-lane) butterfly-free down-reduce
        #pragma unroll
        for (int off = 32; off > 0; off >>= 1) {
            float omax = __shfl_down(lmax, off);
            int   oidx = __shfl_down(lidx, off);
            lsum += __shfl_down(lsum, off);
            lsq  += __shfl_down(lsq,  off);
            lpl  += __shfl_down(lpl,  off);
            if (omax > lmax || (omax == lmax && oidx < lidx)) { lmax = omax; lidx = oidx; }
        }

        if (lane == 0) {
            float conf = lmax / lsum;                       // softmax(log p) max == M/S
            float acc  = (lidx == label) ? 1.f : 0.f;
            float bri  = lsq / (lsum * lsum) - 2.f * (lpl / lsum) + 1.f;
            int bin = (int)ceilf(conf * (float)NBINS) - 1;
            bin = bin < 0 ? 0 : (bin > NBINS - 1 ? NBINS - 1 : bin);
            atomicAdd(&s_cnt[bin],  1.f);
            atomicAdd(&s_conf[bin], conf);
            atomicAdd(&s_acc[bin],  acc);
            wbri += bri;
        }
    }
    if (lane == 0) atomicAdd(&s_bri, wbri);
    __syncthreads();

    if (tid < NBINS) {
        atomicAdd(&g_cnt[tid],  s_cnt[tid]);
        atomicAdd(&g_conf[tid], s_conf[tid]);
        atomicAdd(&g_acc[tid],  s_acc[tid]);
    }
    if (tid == 0) atomicAdd(g_bri, (double)s_bri);
}

__global__ void ece_final(const double* __restrict__ g_bri,
                          const float* __restrict__ g_cnt,
                          const float* __restrict__ g_conf,
                          const float* __restrict__ g_acc,
                          float* __restrict__ out, float invN) {
    if (threadIdx.x == 0 && blockIdx.x == 0) {
        float ece = 0.f, mx = 0.f;
        for (int b = 0; b < NBINS; b++) {
            float c = g_cnt[b];
            float gap = 0.f;
            if (c > 0.f) gap = fabsf(g_conf[b] / c - g_acc[b] / c);
            ece += gap * (c * invN);
            if (gap > mx) mx = gap;
        }
        out[0] = ece;
        out[1] = mx;
        out[2] = (float)(g_bri[0] * (double)invN);
    }
}

extern "C" void kernel_launch(void* const* d_in, const int* in_sizes, int n_in,
                              void* d_out, int out_size, void* d_ws, size_t ws_size,
                              hipStream_t stream) {
    const float* probs  = (const float*)d_in[0];
    const int*   labels = (const int*)d_in[1];
    const int N = in_sizes[1];
    const int C = in_sizes[0] / N;   // 100

    double* g_bri  = (double*)d_ws;
    float*  g_cnt  = (float*)((char*)d_ws + sizeof(double));
    float*  g_conf = g_cnt + NBINS;
    float*  g_acc  = g_conf + NBINS;

    // ws is re-poisoned to 0xAA before every launch — zero the accumulators.
    hipMemsetAsync(d_ws, 0, sizeof(double) + 3 * NBINS * sizeof(float), stream);

    const int blocks = 2048;   // 8192 waves; 2048 end-atomics/bin-address, negligible
    hipLaunchKernelGGL(ece_rows, dim3(blocks), dim3(256), 0, stream,
                       probs, labels, N, C, g_bri, g_cnt, g_conf, g_acc);
    hipLaunchKernelGGL(ece_final, dim3(1), dim3(64), 0, stream,
                       g_bri, g_cnt, g_conf, g_acc, (float*)d_out, 1.f / (float)N);
}

// Round 2
// 555.971 us; speedup vs baseline: 1.4310x; 1.4310x over previous
//
#include <hip/hip_runtime.h>

#define NBINS 15

// Thread-per-row: each thread streams one 400B row as 25 float4 loads,
// reducing sum / sumsq / max+argmax entirely in registers (no cross-lane ops
// in the hot loop). Lanes of a wave cover 64 consecutive rows = 25.6 KB
// contiguous, so every cacheline is fully consumed within a short reuse
// window (L1-resident). Per-row results go to per-block LDS bins, flushed
// once per block to global atomics.
__global__ __launch_bounds__(256) void ece_rows(const float* __restrict__ probs,
                                                const int* __restrict__ labels,
                                                int N, int C,
                                                double* __restrict__ g_bri,
                                                float* __restrict__ g_cnt,
                                                float* __restrict__ g_conf,
                                                float* __restrict__ g_acc) {
    __shared__ float s_cnt[NBINS], s_conf[NBINS], s_acc[NBINS];
    __shared__ float s_bri;
    const int tid = threadIdx.x;
    if (tid < NBINS) { s_cnt[tid] = 0.f; s_conf[tid] = 0.f; s_acc[tid] = 0.f; }
    if (tid == 0) s_bri = 0.f;
    __syncthreads();

    float tbri = 0.f;  // per-thread brier partial
    const int stride = gridDim.x * blockDim.x;

    for (int r = blockIdx.x * blockDim.x + tid; r < N; r += stride) {
        const float* row = probs + (size_t)r * (size_t)C;
        float sum = 0.f, sq = 0.f, vmax = -1.f;
        int imax = 0;

        if (C == 100) {
            const float4* row4 = (const float4*)row;
            #pragma unroll 5
            for (int k = 0; k < 25; k++) {
                float4 v = row4[k];
                sum += (v.x + v.y) + (v.z + v.w);
                sq = fmaf(v.x, v.x, sq);
                sq = fmaf(v.y, v.y, sq);
                sq = fmaf(v.z, v.z, sq);
                sq = fmaf(v.w, v.w, sq);
                int c = k * 4;
                if (v.x > vmax) { vmax = v.x; imax = c; }
                if (v.y > vmax) { vmax = v.y; imax = c + 1; }
                if (v.z > vmax) { vmax = v.z; imax = c + 2; }
                if (v.w > vmax) { vmax = v.w; imax = c + 3; }
            }
        } else {
            for (int c = 0; c < C; c++) {
                float v = row[c];
                sum += v;
                sq = fmaf(v, v, sq);
                if (v > vmax) { vmax = v; imax = c; }
            }
        }

        const int label = labels[r];
        const float pl = row[label];          // L1 hit — row just streamed

        const float inv = 1.f / sum;
        const float conf = vmax * inv;        // max of softmax(log p) == M/S
        const float acc = (imax == label) ? 1.f : 0.f;
        const float bri = sq * inv * inv - 2.f * (pl * inv) + 1.f;

        int bin = (int)ceilf(conf * (float)NBINS) - 1;
        bin = bin < 0 ? 0 : (bin > NBINS - 1 ? NBINS - 1 : bin);

        atomicAdd(&s_cnt[bin], 1.f);
        atomicAdd(&s_conf[bin], conf);
        atomicAdd(&s_acc[bin], acc);
        tbri += bri;
    }

    // wave-reduce brier partials, one LDS add per wave
    #pragma unroll
    for (int off = 32; off > 0; off >>= 1)
        tbri += __shfl_down(tbri, off);
    if ((tid & 63) == 0) atomicAdd(&s_bri, tbri);
    __syncthreads();

    if (tid < NBINS) {
        atomicAdd(&g_cnt[tid], s_cnt[tid]);
        atomicAdd(&g_conf[tid], s_conf[tid]);
        atomicAdd(&g_acc[tid], s_acc[tid]);
    }
    if (tid == 0) atomicAdd(g_bri, (double)s_bri);
}

__global__ void ece_final(const double* __restrict__ g_bri,
                          const float* __restrict__ g_cnt,
                          const float* __restrict__ g_conf,
                          const float* __restrict__ g_acc,
                          float* __restrict__ out, float invN) {
    if (threadIdx.x == 0 && blockIdx.x == 0) {
        float ece = 0.f, mx = 0.f;
        for (int b = 0; b < NBINS; b++) {
            float c = g_cnt[b];
            float gap = 0.f;
            if (c > 0.f) gap = fabsf(g_conf[b] / c - g_acc[b] / c);
            ece += gap * (c * invN);
            if (gap > mx) mx = gap;
        }
        out[0] = ece;
        out[1] = mx;
        out[2] = (float)(g_bri[0] * (double)invN);
    }
}

extern "C" void kernel_launch(void* const* d_in, const int* in_sizes, int n_in,
                              void* d_out, int out_size, void* d_ws, size_t ws_size,
                              hipStream_t stream) {
    const float* probs  = (const float*)d_in[0];
    const int*   labels = (const int*)d_in[1];
    const int N = in_sizes[1];
    const int C = in_sizes[0] / N;   // 100

    double* g_bri  = (double*)d_ws;
    float*  g_cnt  = (float*)((char*)d_ws + sizeof(double));
    float*  g_conf = g_cnt + NBINS;
    float*  g_acc  = g_conf + NBINS;

    // ws is re-poisoned to 0xAA before every launch — zero the accumulators.
    hipMemsetAsync(d_ws, 0, sizeof(double) + 3 * NBINS * sizeof(float), stream);

    const int blocks = 1024;  // 262144 threads, ~4 rows/thread; 1024 global
                              // atomics per bin address at flush (~µs-scale)
    hipLaunchKernelGGL(ece_rows, dim3(blocks), dim3(256), 0, stream,
                       probs, labels, N, C, g_bri, g_cnt, g_conf, g_acc);
    hipLaunchKernelGGL(ece_final, dim3(1), dim3(64), 0, stream,
                       g_bri, g_cnt, g_conf, g_acc, (float*)d_out, 1.f / (float)N);
}